// Round 1
// baseline (339.356 us; speedup 1.0000x reference)
//
#include <hip/hip_runtime.h>
#include <stdint.h>

typedef __attribute__((ext_vector_type(4))) float f32x4;
typedef __attribute__((ext_vector_type(8))) short s16x8;

#define MFMA16(A, B, C) __builtin_amdgcn_mfma_f32_16x16x32_bf16(A, B, C, 0, 0, 0)

__device__ __forceinline__ unsigned short f2bf(float x) {
  union { float f; unsigned u; } v; v.f = x;
  return (unsigned short)((v.u + 0x7fffu + ((v.u >> 16) & 1u)) >> 16);
}

// ---------------- cast f32 -> bf16, 4 elems/thread ----------------
__global__ void k_cast_bf16(const float* __restrict__ in, unsigned short* __restrict__ out, int n4) {
  int i = blockIdx.x * blockDim.x + threadIdx.x;
  const int stride = gridDim.x * blockDim.x;
  for (; i < n4; i += stride) {
    const float4 v = ((const float4*)in)[i];
    ushort4 o;
    o.x = f2bf(v.x); o.y = f2bf(v.y); o.z = f2bf(v.z); o.w = f2bf(v.w);
    ((ushort4*)out)[i] = o;
  }
}

// ---------------- exc [16384][28] -> excT bf16 [32][16384] (rows 28..31 = 0) + b[28] ----------------
__global__ void k_excT(const float* __restrict__ exc, unsigned short* __restrict__ excT,
                       float* __restrict__ bvec) {
  const int c = blockIdx.x;        // 0..31
  const int tid = threadIdx.x;     // 256
  float sum = 0.f;
  for (int j = tid; j < 16384; j += 256) {
    const float v = (c < 28) ? exc[(size_t)j * 28 + c] : 0.f;
    excT[(size_t)c * 16384 + j] = f2bf(v);
    sum += v;
  }
  #pragma unroll
  for (int o = 32; o; o >>= 1) sum += __shfl_down(sum, o, 64);
  __shared__ float wsum[4];
  if ((tid & 63) == 0) wsum[tid >> 6] = sum;
  __syncthreads();
  if (tid == 0 && c < 28) bvec[c] = fmaxf(wsum[0] + wsum[1] + wsum[2] + wsum[3], 1.0f);
}

// ---------------- stage a 128x64 bf16 tile (row-major, ld elements) into LDS ----------------
__device__ __forceinline__ void stage_tile(const unsigned short* __restrict__ src, int ld,
                                           unsigned short* lds, int wave, int lane) {
  const int rowin = lane >> 3, cb = lane & 7;  // 8 rows x 8 16B-blocks per 1KB chunk
  #pragma unroll
  for (int c = 0; c < 4; ++c) {
    const int chunk = wave * 4 + c;
    const unsigned short* g = src + (size_t)(chunk * 8 + rowin) * ld + cb * 8;
    __builtin_amdgcn_global_load_lds((const __attribute__((address_space(1))) unsigned int*)g,
                                     (__attribute__((address_space(3))) unsigned int*)(lds + chunk * 512),
                                     16, 0, 0);
  }
}

// ---------------- one BK=64 MFMA step: 128x128 tile, 4 waves (2x2), 4x4 frags/wave ----------------
__device__ __forceinline__ void mma_tile(const unsigned short* As, const unsigned short* Bs,
                                         int wr, int wc, int r, int q, f32x4 acc[4][4]) {
  #pragma unroll
  for (int ks = 0; ks < 64; ks += 32) {
    s16x8 af[4], bf[4];
    #pragma unroll
    for (int i = 0; i < 4; ++i)
      af[i] = *(const s16x8*)(As + ((wr * 64 + i * 16 + r) * 64 + ks + q * 8));
    #pragma unroll
    for (int j = 0; j < 4; ++j)
      bf[j] = *(const s16x8*)(Bs + ((wc * 64 + j * 16 + r) * 64 + ks + q * 8));
    #pragma unroll
    for (int i = 0; i < 4; ++i)
      #pragma unroll
      for (int j = 0; j < 4; ++j)
        acc[i][j] = MFMA16(af[i], bf[j], acc[i][j]);
  }
}

// ---------------- proj: f_all[24576][512] = [feat;ex_feat] @ g_w^T + g_b ----------------
__global__ __launch_bounds__(256) void k_proj(const unsigned short* __restrict__ featbf,
                                              const unsigned short* __restrict__ exbf,
                                              const unsigned short* __restrict__ gwbf,
                                              const float* __restrict__ gb,
                                              float* __restrict__ fall) {
  __shared__ __align__(16) unsigned short As[128 * 64];
  __shared__ __align__(16) unsigned short Bs[128 * 64];
  const int tid = threadIdx.x, wave = tid >> 6, lane = tid & 63;
  const int wr = wave >> 1, wc = wave & 1, r = lane & 15, q = lane >> 4;
  const int m0 = blockIdx.x * 128;  // row in concat(features, ex_features)
  const int n0 = blockIdx.y * 128;
  const unsigned short* Asrc = (m0 < 8192) ? (featbf + (size_t)m0 * 1024)
                                           : (exbf + (size_t)(m0 - 8192) * 1024);
  const unsigned short* Bsrc = gwbf + (size_t)n0 * 1024;
  f32x4 acc[4][4];
  #pragma unroll
  for (int i = 0; i < 4; ++i)
    #pragma unroll
    for (int j = 0; j < 4; ++j) acc[i][j] = {0.f, 0.f, 0.f, 0.f};
  for (int kk = 0; kk < 1024; kk += 64) {
    stage_tile(Asrc + kk, 1024, As, wave, lane);
    stage_tile(Bsrc + kk, 1024, Bs, wave, lane);
    __syncthreads();
    mma_tile(As, Bs, wr, wc, r, q, acc);
    __syncthreads();
  }
  #pragma unroll
  for (int j = 0; j < 4; ++j) {
    const int col = n0 + wc * 64 + j * 16 + r;
    const float bias = gb[col];
    #pragma unroll
    for (int i = 0; i < 4; ++i) {
      const int row0 = m0 + wr * 64 + i * 16 + q * 4;
      #pragma unroll
      for (int t = 0; t < 4; ++t)
        fall[(size_t)(row0 + t) * 512 + col] = acc[i][j][t] + bias;
    }
  }
}

// ---------------- normalize rows of f_all (512) -> bf16 fn_all ----------------
__global__ __launch_bounds__(256) void k_norm(const float* __restrict__ fall,
                                              unsigned short* __restrict__ fn) {
  const int row = blockIdx.x * 4 + (threadIdx.x >> 6);
  const int lane = threadIdx.x & 63;
  const float4* p = (const float4*)(fall + (size_t)row * 512) + lane * 2;
  const float4 v0 = p[0], v1 = p[1];
  float ss = v0.x * v0.x + v0.y * v0.y + v0.z * v0.z + v0.w * v0.w
           + v1.x * v1.x + v1.y * v1.y + v1.z * v1.z + v1.w * v1.w;
  #pragma unroll
  for (int o = 32; o; o >>= 1) ss += __shfl_xor(ss, o, 64);
  const float sc = 1.0f / fmaxf(sqrtf(ss), 1e-12f);
  ushort4 o0, o1;
  o0.x = f2bf(v0.x * sc); o0.y = f2bf(v0.y * sc); o0.z = f2bf(v0.z * sc); o0.w = f2bf(v0.w * sc);
  o1.x = f2bf(v1.x * sc); o1.y = f2bf(v1.y * sc); o1.z = f2bf(v1.z * sc); o1.w = f2bf(v1.w * sc);
  ushort4* qo = (ushort4*)(fn + (size_t)row * 512) + lane * 2;
  qo[0] = o0; qo[1] = o1;
}

// ---------------- fused: s = fn @ efn^T, a = s^3, echo_partial += a @ excT^T ----------------
__global__ __launch_bounds__(256) void k_fused(const unsigned short* __restrict__ fnall,
                                               const unsigned short* __restrict__ excT,
                                               float* __restrict__ partial) {
  __shared__ __align__(16) unsigned short smem[17408];  // max(As+Bs=16384, aL=128*136=17408) shorts
  unsigned short* As = smem;
  unsigned short* Bs = smem + 8192;
  unsigned short* aL = smem;  // [128][136] bf16, aliases staging buffers (time-disjoint)
  const int tid = threadIdx.x, wave = tid >> 6, lane = tid & 63;
  const int wr = wave >> 1, wc = wave & 1, r = lane & 15, q = lane >> 4;
  const int r0 = blockIdx.x * 128;     // 64 M-tiles
  const int nchunk = blockIdx.y;       // 16 N-chunks of 8 j-tiles
  const unsigned short* Abase = fnall + (size_t)r0 * 512;
  const unsigned short* Ebase = fnall + (size_t)8192 * 512;
  f32x4 eacc[2][2];
  #pragma unroll
  for (int a = 0; a < 2; ++a)
    #pragma unroll
    for (int b = 0; b < 2; ++b) eacc[a][b] = {0.f, 0.f, 0.f, 0.f};

  for (int jt = 0; jt < 8; ++jt) {
    const int c0 = (nchunk * 8 + jt) * 128;
    const unsigned short* Bsrc = Ebase + (size_t)c0 * 512;
    f32x4 acc[4][4];
    #pragma unroll
    for (int i = 0; i < 4; ++i)
      #pragma unroll
      for (int j = 0; j < 4; ++j) acc[i][j] = {0.f, 0.f, 0.f, 0.f};
    for (int kk = 0; kk < 512; kk += 64) {
      stage_tile(Abase + kk, 512, As, wave, lane);
      stage_tile(Bsrc + kk, 512, Bs, wave, lane);
      __syncthreads();
      mma_tile(As, Bs, wr, wc, r, q, acc);
      __syncthreads();
    }
    // cube -> aL (bf16), layout [row][col] stride 136
    #pragma unroll
    for (int i = 0; i < 4; ++i)
      #pragma unroll
      for (int j = 0; j < 4; ++j) {
        const int row0 = wr * 64 + i * 16 + q * 4;
        const int col = wc * 64 + j * 16 + r;
        #pragma unroll
        for (int t = 0; t < 4; ++t) {
          const float v = acc[i][j][t];
          aL[(row0 + t) * 136 + col] = f2bf(v * v * v);
        }
      }
    __syncthreads();
    // echo MFMA: wave handles rows 32*wave..+31; K = 128 tile cols; N = 32 classes
    #pragma unroll
    for (int kc = 0; kc < 4; ++kc) {
      s16x8 af[2], bfr[2];
      #pragma unroll
      for (int mi = 0; mi < 2; ++mi)
        af[mi] = *(const s16x8*)(aL + (wave * 32 + mi * 16 + r) * 136 + kc * 32 + q * 8);
      #pragma unroll
      for (int nj = 0; nj < 2; ++nj)
        bfr[nj] = *(const s16x8*)(excT + (size_t)(nj * 16 + r) * 16384 + c0 + kc * 32 + q * 8);
      #pragma unroll
      for (int mi = 0; mi < 2; ++mi)
        #pragma unroll
        for (int nj = 0; nj < 2; ++nj)
          eacc[mi][nj] = MFMA16(af[mi], bfr[nj], eacc[mi][nj]);
    }
    __syncthreads();
  }
  // write partial [nchunk][8192][32]
  #pragma unroll
  for (int mi = 0; mi < 2; ++mi)
    #pragma unroll
    for (int nj = 0; nj < 2; ++nj) {
      const int row0 = r0 + wave * 32 + mi * 16 + q * 4;
      const int cls = nj * 16 + r;
      #pragma unroll
      for (int t = 0; t < 4; ++t)
        partial[((size_t)nchunk * 8192 + row0 + t) * 32 + cls] = eacc[mi][nj][t];
    }
}

// ---------------- reduce 16 partials, /b, clip ----------------
__global__ void k_reduce(const float* __restrict__ partial, const float* __restrict__ bvec,
                         float* __restrict__ out) {
  const int idx = blockIdx.x * 256 + threadIdx.x;  // 229376 total
  const int row = idx / 28, c = idx - row * 28;
  float s = 0.f;
  #pragma unroll
  for (int nc = 0; nc < 16; ++nc) s += partial[((size_t)nc * 8192 + row) * 32 + c];
  out[idx] = fminf(fmaxf(s / bvec[c], 0.f), 1.f);
}

extern "C" void kernel_launch(void* const* d_in, const int* in_sizes, int n_in,
                              void* d_out, int out_size, void* d_ws, size_t ws_size,
                              hipStream_t stream) {
  const float* features    = (const float*)d_in[0];  // [8192,1024]
  const float* ex_features = (const float*)d_in[1];  // [16384,1024]
  const float* g_w         = (const float*)d_in[2];  // [512,1024]
  const float* g_b         = (const float*)d_in[3];  // [512]
  const float* ex_classes  = (const float*)d_in[4];  // [16384,28]
  float* out = (float*)d_out;
  char* ws = (char*)d_ws;

  // ws layout (time-multiplexed):
  //  [0,16M)       featbf        -> later fn_all bf16 [24576][512] (25.2MB)
  //  [16M,50.3M)   exbf
  //  [50.3M,100.6M) f_all f32    -> later partial [16][8192][32] f32 (16.8MB)
  //  [100.6M,...)  gwbf (1MB), excT (1MB), bvec
  unsigned short* featbf = (unsigned short*)(ws + 0);
  unsigned short* exbf   = (unsigned short*)(ws + 16777216);
  unsigned short* fnall  = (unsigned short*)(ws + 0);
  float* fall            = (float*)(ws + 50331648);
  float* partial         = (float*)(ws + 50331648);
  unsigned short* gwbf   = (unsigned short*)(ws + 100663296);
  unsigned short* excT   = (unsigned short*)(ws + 101711872);
  float* bvec            = (float*)(ws + 102760448);

  k_cast_bf16<<<2048, 256, 0, stream>>>(features, featbf, 8192 * 1024 / 4);
  k_cast_bf16<<<2048, 256, 0, stream>>>(ex_features, exbf, 16384 * 1024 / 4);
  k_cast_bf16<<<512, 256, 0, stream>>>(g_w, gwbf, 512 * 1024 / 4);
  k_excT<<<32, 256, 0, stream>>>(ex_classes, excT, bvec);
  k_proj<<<dim3(192, 4), 256, 0, stream>>>(featbf, exbf, gwbf, g_b, fall);
  k_norm<<<6144, 256, 0, stream>>>(fall, fnall);
  k_fused<<<dim3(64, 16), 256, 0, stream>>>(fnall, excT, partial);
  k_reduce<<<896, 256, 0, stream>>>(partial, bvec, out);
}

// Round 2
// 313.598 us; speedup vs baseline: 1.0821x; 1.0821x over previous
//
#include <hip/hip_runtime.h>
#include <stdint.h>

typedef __attribute__((ext_vector_type(4))) float f32x4;
typedef __attribute__((ext_vector_type(8))) short s16x8;

#define MFMA16(A, B, C) __builtin_amdgcn_mfma_f32_16x16x32_bf16(A, B, C, 0, 0, 0)

__device__ __forceinline__ unsigned short f2bf(float x) {
  union { float f; unsigned u; } v; v.f = x;
  return (unsigned short)((v.u + 0x7fffu + ((v.u >> 16) & 1u)) >> 16);
}

// ---------------- cast f32 -> bf16, 4 elems/thread ----------------
__global__ void k_cast_bf16(const float* __restrict__ in, unsigned short* __restrict__ out, int n4) {
  int i = blockIdx.x * blockDim.x + threadIdx.x;
  const int stride = gridDim.x * blockDim.x;
  for (; i < n4; i += stride) {
    const float4 v = ((const float4*)in)[i];
    ushort4 o;
    o.x = f2bf(v.x); o.y = f2bf(v.y); o.z = f2bf(v.z); o.w = f2bf(v.w);
    ((ushort4*)out)[i] = o;
  }
}

// ---------------- exc [16384][28] -> excT bf16 [32][16384] (rows 28..31 = 0) + b[28] ----------------
__global__ void k_excT(const float* __restrict__ exc, unsigned short* __restrict__ excT,
                       float* __restrict__ bvec) {
  const int c = blockIdx.x;        // 0..31
  const int tid = threadIdx.x;     // 256
  float sum = 0.f;
  for (int j = tid; j < 16384; j += 256) {
    const float v = (c < 28) ? exc[(size_t)j * 28 + c] : 0.f;
    excT[(size_t)c * 16384 + j] = f2bf(v);
    sum += v;
  }
  #pragma unroll
  for (int o = 32; o; o >>= 1) sum += __shfl_down(sum, o, 64);
  __shared__ float wsum[4];
  if ((tid & 63) == 0) wsum[tid >> 6] = sum;
  __syncthreads();
  if (tid == 0 && c < 28) bvec[c] = fmaxf(wsum[0] + wsum[1] + wsum[2] + wsum[3], 1.0f);
}

// ---------------- stage a 128x64 bf16 tile into LDS, XOR-swizzled ----------------
// LDS[row][blk] (blk = 16B unit, 8 per row) holds global block (blk ^ (row&7)).
// global_load_lds writes linearly (base + lane*16B); we pre-swizzle the SOURCE.
__device__ __forceinline__ void stage_tile(const unsigned short* __restrict__ src, int ld,
                                           unsigned short* lds, int wave, int lane) {
  const int rowin = lane >> 3, cb = lane & 7;  // 8 rows x 8 16B-blocks per 1KB chunk
  const int scb = cb ^ rowin;                  // pre-swizzled source block
  #pragma unroll
  for (int c = 0; c < 4; ++c) {
    const int chunk = wave * 4 + c;
    const unsigned short* g = src + (size_t)(chunk * 8 + rowin) * ld + scb * 8;
    __builtin_amdgcn_global_load_lds((const __attribute__((address_space(1))) unsigned int*)g,
                                     (__attribute__((address_space(3))) unsigned int*)(lds + chunk * 512),
                                     16, 0, 0);
  }
}

// ---------------- one BK=64 MFMA step: 128x128 tile, 4 waves (2x2), 4x4 frags/wave ----------------
// Reads apply the matching XOR: global block gb lives at LDS blk = gb ^ (row&7).
__device__ __forceinline__ void mma_tile(const unsigned short* As, const unsigned short* Bs,
                                         int wr, int wc, int r, int q, f32x4 acc[4][4]) {
  const int rx = r & 7;
  #pragma unroll
  for (int ks = 0; ks < 64; ks += 32) {
    const int gb = (ks >> 3) + q;        // global 16B-block index within the row
    const int sb = (gb ^ rx) << 3;       // swizzled LDS offset (shorts)
    s16x8 af[4], bf[4];
    #pragma unroll
    for (int i = 0; i < 4; ++i)
      af[i] = *(const s16x8*)(As + ((wr * 64 + i * 16 + r) * 64 + sb));
    #pragma unroll
    for (int j = 0; j < 4; ++j)
      bf[j] = *(const s16x8*)(Bs + ((wc * 64 + j * 16 + r) * 64 + sb));
    #pragma unroll
    for (int i = 0; i < 4; ++i)
      #pragma unroll
      for (int j = 0; j < 4; ++j)
        acc[i][j] = MFMA16(af[i], bf[j], acc[i][j]);
  }
}

// ---------------- proj: f_all[24576][512] = [feat;ex_feat] @ g_w^T + g_b ----------------
__global__ __launch_bounds__(256) void k_proj(const unsigned short* __restrict__ featbf,
                                              const unsigned short* __restrict__ exbf,
                                              const unsigned short* __restrict__ gwbf,
                                              const float* __restrict__ gb,
                                              float* __restrict__ fall) {
  __shared__ __align__(16) unsigned short As[128 * 64];
  __shared__ __align__(16) unsigned short Bs[128 * 64];
  const int tid = threadIdx.x, wave = tid >> 6, lane = tid & 63;
  const int wr = wave >> 1, wc = wave & 1, r = lane & 15, q = lane >> 4;
  const int m0 = blockIdx.x * 128;  // row in concat(features, ex_features)
  const int n0 = blockIdx.y * 128;
  const unsigned short* Asrc = (m0 < 8192) ? (featbf + (size_t)m0 * 1024)
                                           : (exbf + (size_t)(m0 - 8192) * 1024);
  const unsigned short* Bsrc = gwbf + (size_t)n0 * 1024;
  f32x4 acc[4][4];
  #pragma unroll
  for (int i = 0; i < 4; ++i)
    #pragma unroll
    for (int j = 0; j < 4; ++j) acc[i][j] = {0.f, 0.f, 0.f, 0.f};
  for (int kk = 0; kk < 1024; kk += 64) {
    stage_tile(Asrc + kk, 1024, As, wave, lane);
    stage_tile(Bsrc + kk, 1024, Bs, wave, lane);
    __syncthreads();
    mma_tile(As, Bs, wr, wc, r, q, acc);
    __syncthreads();
  }
  #pragma unroll
  for (int j = 0; j < 4; ++j) {
    const int col = n0 + wc * 64 + j * 16 + r;
    const float bias = gb[col];
    #pragma unroll
    for (int i = 0; i < 4; ++i) {
      const int row0 = m0 + wr * 64 + i * 16 + q * 4;
      #pragma unroll
      for (int t = 0; t < 4; ++t)
        fall[(size_t)(row0 + t) * 512 + col] = acc[i][j][t] + bias;
    }
  }
}

// ---------------- normalize rows of f_all (512) -> bf16 fn_all ----------------
__global__ __launch_bounds__(256) void k_norm(const float* __restrict__ fall,
                                              unsigned short* __restrict__ fn) {
  const int row = blockIdx.x * 4 + (threadIdx.x >> 6);
  const int lane = threadIdx.x & 63;
  const float4* p = (const float4*)(fall + (size_t)row * 512) + lane * 2;
  const float4 v0 = p[0], v1 = p[1];
  float ss = v0.x * v0.x + v0.y * v0.y + v0.z * v0.z + v0.w * v0.w
           + v1.x * v1.x + v1.y * v1.y + v1.z * v1.z + v1.w * v1.w;
  #pragma unroll
  for (int o = 32; o; o >>= 1) ss += __shfl_xor(ss, o, 64);
  const float sc = 1.0f / fmaxf(sqrtf(ss), 1e-12f);
  ushort4 o0, o1;
  o0.x = f2bf(v0.x * sc); o0.y = f2bf(v0.y * sc); o0.z = f2bf(v0.z * sc); o0.w = f2bf(v0.w * sc);
  o1.x = f2bf(v1.x * sc); o1.y = f2bf(v1.y * sc); o1.z = f2bf(v1.z * sc); o1.w = f2bf(v1.w * sc);
  ushort4* qo = (ushort4*)(fn + (size_t)row * 512) + lane * 2;
  qo[0] = o0; qo[1] = o1;
}

// ---------------- fused: s = fn @ efn^T, a = s^3, echo_partial += a @ excT^T ----------------
__global__ __launch_bounds__(256) void k_fused(const unsigned short* __restrict__ fnall,
                                               const unsigned short* __restrict__ excT,
                                               float* __restrict__ partial) {
  __shared__ __align__(16) unsigned short smem[17408];  // max(As+Bs=16384, aL=128*136=17408) shorts
  unsigned short* As = smem;
  unsigned short* Bs = smem + 8192;
  unsigned short* aL = smem;  // [128][136] bf16, aliases staging buffers (time-disjoint)
  const int tid = threadIdx.x, wave = tid >> 6, lane = tid & 63;
  const int wr = wave >> 1, wc = wave & 1, r = lane & 15, q = lane >> 4;
  const int r0 = blockIdx.x * 128;     // 64 M-tiles
  const int nchunk = blockIdx.y;       // 16 N-chunks of 8 j-tiles
  const unsigned short* Abase = fnall + (size_t)r0 * 512;
  const unsigned short* Ebase = fnall + (size_t)8192 * 512;
  f32x4 eacc[2][2];
  #pragma unroll
  for (int a = 0; a < 2; ++a)
    #pragma unroll
    for (int b = 0; b < 2; ++b) eacc[a][b] = {0.f, 0.f, 0.f, 0.f};

  for (int jt = 0; jt < 8; ++jt) {
    const int c0 = (nchunk * 8 + jt) * 128;
    const unsigned short* Bsrc = Ebase + (size_t)c0 * 512;
    f32x4 acc[4][4];
    #pragma unroll
    for (int i = 0; i < 4; ++i)
      #pragma unroll
      for (int j = 0; j < 4; ++j) acc[i][j] = {0.f, 0.f, 0.f, 0.f};
    for (int kk = 0; kk < 512; kk += 64) {
      stage_tile(Abase + kk, 512, As, wave, lane);
      stage_tile(Bsrc + kk, 512, Bs, wave, lane);
      __syncthreads();
      mma_tile(As, Bs, wr, wc, r, q, acc);
      __syncthreads();
    }
    // cube -> aL (bf16), layout [row][col] stride 136
    #pragma unroll
    for (int i = 0; i < 4; ++i)
      #pragma unroll
      for (int j = 0; j < 4; ++j) {
        const int row0 = wr * 64 + i * 16 + q * 4;
        const int col = wc * 64 + j * 16 + r;
        #pragma unroll
        for (int t = 0; t < 4; ++t) {
          const float v = acc[i][j][t];
          aL[(row0 + t) * 136 + col] = f2bf(v * v * v);
        }
      }
    __syncthreads();
    // echo MFMA: wave handles rows 32*wave..+31; K = 128 tile cols; N = 32 classes
    #pragma unroll
    for (int kc = 0; kc < 4; ++kc) {
      s16x8 af[2], bfr[2];
      #pragma unroll
      for (int mi = 0; mi < 2; ++mi)
        af[mi] = *(const s16x8*)(aL + (wave * 32 + mi * 16 + r) * 136 + kc * 32 + q * 8);
      #pragma unroll
      for (int nj = 0; nj < 2; ++nj)
        bfr[nj] = *(const s16x8*)(excT + (size_t)(nj * 16 + r) * 16384 + c0 + kc * 32 + q * 8);
      #pragma unroll
      for (int mi = 0; mi < 2; ++mi)
        #pragma unroll
        for (int nj = 0; nj < 2; ++nj)
          eacc[mi][nj] = MFMA16(af[mi], bfr[nj], eacc[mi][nj]);
    }
    __syncthreads();
  }
  // write partial [nchunk][8192][32]
  #pragma unroll
  for (int mi = 0; mi < 2; ++mi)
    #pragma unroll
    for (int nj = 0; nj < 2; ++nj) {
      const int row0 = r0 + wave * 32 + mi * 16 + q * 4;
      const int cls = nj * 16 + r;
      #pragma unroll
      for (int t = 0; t < 4; ++t)
        partial[((size_t)nchunk * 8192 + row0 + t) * 32 + cls] = eacc[mi][nj][t];
    }
}

// ---------------- reduce 16 partials, /b, clip ----------------
__global__ void k_reduce(const float* __restrict__ partial, const float* __restrict__ bvec,
                         float* __restrict__ out) {
  const int idx = blockIdx.x * 256 + threadIdx.x;  // 229376 total
  const int row = idx / 28, c = idx - row * 28;
  float s = 0.f;
  #pragma unroll
  for (int nc = 0; nc < 16; ++nc) s += partial[((size_t)nc * 8192 + row) * 32 + c];
  out[idx] = fminf(fmaxf(s / bvec[c], 0.f), 1.f);
}

extern "C" void kernel_launch(void* const* d_in, const int* in_sizes, int n_in,
                              void* d_out, int out_size, void* d_ws, size_t ws_size,
                              hipStream_t stream) {
  const float* features    = (const float*)d_in[0];  // [8192,1024]
  const float* ex_features = (const float*)d_in[1];  // [16384,1024]
  const float* g_w         = (const float*)d_in[2];  // [512,1024]
  const float* g_b         = (const float*)d_in[3];  // [512]
  const float* ex_classes  = (const float*)d_in[4];  // [16384,28]
  float* out = (float*)d_out;
  char* ws = (char*)d_ws;

  // ws layout (time-multiplexed):
  //  [0,16M)       featbf        -> later fn_all bf16 [24576][512] (25.2MB)
  //  [16M,50.3M)   exbf
  //  [50.3M,100.6M) f_all f32    -> later partial [16][8192][32] f32 (16.8MB)
  //  [100.6M,...)  gwbf (1MB), excT (1MB), bvec
  unsigned short* featbf = (unsigned short*)(ws + 0);
  unsigned short* exbf   = (unsigned short*)(ws + 16777216);
  unsigned short* fnall  = (unsigned short*)(ws + 0);
  float* fall            = (float*)(ws + 50331648);
  float* partial         = (float*)(ws + 50331648);
  unsigned short* gwbf   = (unsigned short*)(ws + 100663296);
  unsigned short* excT   = (unsigned short*)(ws + 101711872);
  float* bvec            = (float*)(ws + 102760448);

  k_cast_bf16<<<2048, 256, 0, stream>>>(features, featbf, 8192 * 1024 / 4);
  k_cast_bf16<<<2048, 256, 0, stream>>>(ex_features, exbf, 16384 * 1024 / 4);
  k_cast_bf16<<<512, 256, 0, stream>>>(g_w, gwbf, 512 * 1024 / 4);
  k_excT<<<32, 256, 0, stream>>>(ex_classes, excT, bvec);
  k_proj<<<dim3(192, 4), 256, 0, stream>>>(featbf, exbf, gwbf, g_b, fall);
  k_norm<<<6144, 256, 0, stream>>>(fall, fnall);
  k_fused<<<dim3(64, 16), 256, 0, stream>>>(fnall, excT, partial);
  k_reduce<<<896, 256, 0, stream>>>(partial, bvec, out);
}